// Round 1
// baseline (286.455 us; speedup 1.0000x reference)
//
#include <hip/hip_runtime.h>
#include <math.h>

// Problem constants (from reference)
#define NNB 16   // neighbors
#define NOB 8    // obstacles
#define SDIM 4   // state dim
#define H1D 64   // hidden 1
#define ED 16    // embedding
#define HPD 64   // psi hidden
#define XW (1 + SDIM + SDIM*NNB + 2*NOB)  // 85 floats per row

__global__ __launch_bounds__(256) void barrier_net_kernel(
    const float* __restrict__ x,
    const float* __restrict__ Wp1n, const float* __restrict__ bp1n,
    const float* __restrict__ Wp2n, const float* __restrict__ bp2n,
    const float* __restrict__ Wr1n, const float* __restrict__ br1n,
    const float* __restrict__ Wr2n, const float* __restrict__ br2n,
    const float* __restrict__ Wp1o, const float* __restrict__ bp1o,
    const float* __restrict__ Wp2o, const float* __restrict__ bp2o,
    const float* __restrict__ Wr1o, const float* __restrict__ br1o,
    const float* __restrict__ Wr2o, const float* __restrict__ br2o,
    const float* __restrict__ Wpsi1, const float* __restrict__ bpsi1,
    const float* __restrict__ Wpsi2, const float* __restrict__ bpsi2,
    float* __restrict__ out, int nb)
{
    int row = blockIdx.x * blockDim.x + threadIdx.x;
    if (row >= nb) return;
    const float* xr = x + (size_t)row * XW;

    // goal vector
    float g0 = xr[1], g1 = xr[2], g2 = xr[3], g3 = xr[4];

    // ---------------- neighbor deepset: sum_i phi(nbr_i), fused barrier ----
    float phin[ED];
    #pragma unroll
    for (int j = 0; j < ED; ++j) phin[j] = 0.f;
    float barx = 0.f, bary = 0.f;

    for (int n = 0; n < NNB; ++n) {
        float e0 = xr[1 + SDIM + n*SDIM + 0];
        float e1 = xr[1 + SDIM + n*SDIM + 1];
        float e2 = xr[1 + SDIM + n*SDIM + 2];
        float e3 = xr[1 + SDIM + n*SDIM + 3];

        // barrier term on P = -nbr[:2], D_ROBOT = 0.3
        {
            float px = -e0, py = -e1;
            float nrm = sqrtf(px*px + py*py);
            float Hh  = nrm - 0.3f;
            float coef = 0.05f / (nrm * Hh);
            barx += coef * px;
            bary += coef * py;
        }

        // phi: relu(el @ Wp1n + bp1n) @ Wp2n  (bias bp2n folded in after loop)
        for (int k = 0; k < H1D; ++k) {
            float h = bp1n[k];
            h += e0 * Wp1n[0*H1D + k];
            h += e1 * Wp1n[1*H1D + k];
            h += e2 * Wp1n[2*H1D + k];
            h += e3 * Wp1n[3*H1D + k];
            h = fmaxf(h, 0.f);
            const float* w2 = Wp2n + k*ED;
            #pragma unroll
            for (int j = 0; j < ED; ++j) phin[j] += h * w2[j];
        }
    }
    #pragma unroll
    for (int j = 0; j < ED; ++j) phin[j] += (float)NNB * bp2n[j];

    // rho_n = relu(phin @ Wr1n + br1n) @ Wr2n + br2n
    float rhon[ED];
    #pragma unroll
    for (int j = 0; j < ED; ++j) rhon[j] = br2n[j];
    for (int k = 0; k < H1D; ++k) {
        float h = br1n[k];
        #pragma unroll
        for (int j = 0; j < ED; ++j) h += phin[j] * Wr1n[j*H1D + k];
        h = fmaxf(h, 0.f);
        const float* w2 = Wr2n + k*ED;
        #pragma unroll
        for (int j = 0; j < ED; ++j) rhon[j] += h * w2[j];
    }

    // ---------------- obstacle deepset, fused barrier ----------------------
    float phio[ED];
    #pragma unroll
    for (int j = 0; j < ED; ++j) phio[j] = 0.f;

    const int obs_off = 1 + SDIM + SDIM*NNB;  // 69
    for (int n = 0; n < NOB; ++n) {
        float e0 = xr[obs_off + n*2 + 0];
        float e1 = xr[obs_off + n*2 + 1];

        // barrier term on P = -obs, D_OBST = 0.3
        {
            float px = -e0, py = -e1;
            float nrm = sqrtf(px*px + py*py);
            float Hh  = nrm - 0.3f;
            float coef = 0.05f / (nrm * Hh);
            barx += coef * px;
            bary += coef * py;
        }

        for (int k = 0; k < H1D; ++k) {
            float h = bp1o[k];
            h += e0 * Wp1o[0*H1D + k];
            h += e1 * Wp1o[1*H1D + k];
            h = fmaxf(h, 0.f);
            const float* w2 = Wp2o + k*ED;
            #pragma unroll
            for (int j = 0; j < ED; ++j) phio[j] += h * w2[j];
        }
    }
    #pragma unroll
    for (int j = 0; j < ED; ++j) phio[j] += (float)NOB * bp2o[j];

    // rho_o
    float rhoo[ED];
    #pragma unroll
    for (int j = 0; j < ED; ++j) rhoo[j] = br2o[j];
    for (int k = 0; k < H1D; ++k) {
        float h = br1o[k];
        #pragma unroll
        for (int j = 0; j < ED; ++j) h += phio[j] * Wr1o[j*H1D + k];
        h = fmaxf(h, 0.f);
        const float* w2 = Wr2o + k*ED;
        #pragma unroll
        for (int j = 0; j < ED; ++j) rhoo[j] += h * w2[j];
    }

    // ---------------- psi head: h = [rho_n, rho_o, g] (36) -----------------
    float a0 = bpsi2[0], a1 = bpsi2[1];
    for (int k = 0; k < HPD; ++k) {
        float h = bpsi1[k];
        #pragma unroll
        for (int j = 0; j < ED; ++j) h += rhon[j] * Wpsi1[j*HPD + k];
        #pragma unroll
        for (int j = 0; j < ED; ++j) h += rhoo[j] * Wpsi1[(ED + j)*HPD + k];
        h += g0 * Wpsi1[(2*ED + 0)*HPD + k];
        h += g1 * Wpsi1[(2*ED + 1)*HPD + k];
        h += g2 * Wpsi1[(2*ED + 2)*HPD + k];
        h += g3 * Wpsi1[(2*ED + 3)*HPD + k];
        h = fmaxf(h, 0.f);
        a0 += h * Wpsi2[k*2 + 0];
        a1 += h * Wpsi2[k*2 + 1];
    }

    // emp = (tanh(a)+1)/2 * (PHI_MAX-PHI_MIN) + PHI_MIN  ==  2*tanh(a)
    a0 = 2.f * tanhf(a0);
    a1 = 2.f * tanhf(a1);

    // action = emp + barrier_sum; scale by inv_alpha
    a0 += barx;
    a1 += bary;
    float amax = fmaxf(fabsf(a0), fabsf(a1));
    float inv_alpha = fmaxf(amax * 0.5f, 1.0f);  // A_MAX = 2.0
    float r = 1.0f / inv_alpha;

    out[(size_t)row*2 + 0] = a0 * r;
    out[(size_t)row*2 + 1] = a1 * r;
}

extern "C" void kernel_launch(void* const* d_in, const int* in_sizes, int n_in,
                              void* d_out, int out_size, void* d_ws, size_t ws_size,
                              hipStream_t stream) {
    const float* x     = (const float*)d_in[0];
    const float* Wp1n  = (const float*)d_in[1];
    const float* bp1n  = (const float*)d_in[2];
    const float* Wp2n  = (const float*)d_in[3];
    const float* bp2n  = (const float*)d_in[4];
    const float* Wr1n  = (const float*)d_in[5];
    const float* br1n  = (const float*)d_in[6];
    const float* Wr2n  = (const float*)d_in[7];
    const float* br2n  = (const float*)d_in[8];
    const float* Wp1o  = (const float*)d_in[9];
    const float* bp1o  = (const float*)d_in[10];
    const float* Wp2o  = (const float*)d_in[11];
    const float* bp2o  = (const float*)d_in[12];
    const float* Wr1o  = (const float*)d_in[13];
    const float* br1o  = (const float*)d_in[14];
    const float* Wr2o  = (const float*)d_in[15];
    const float* br2o  = (const float*)d_in[16];
    const float* Wpsi1 = (const float*)d_in[17];
    const float* bpsi1 = (const float*)d_in[18];
    const float* Wpsi2 = (const float*)d_in[19];
    const float* bpsi2 = (const float*)d_in[20];
    float* out = (float*)d_out;

    int nb = in_sizes[0] / XW;   // 131072
    int block = 256;
    int grid = (nb + block - 1) / block;
    barrier_net_kernel<<<grid, block, 0, stream>>>(
        x, Wp1n, bp1n, Wp2n, bp2n, Wr1n, br1n, Wr2n, br2n,
        Wp1o, bp1o, Wp2o, bp2o, Wr1o, br1o, Wr2o, br2o,
        Wpsi1, bpsi1, Wpsi2, bpsi2, out, nb);
}

// Round 2
// 259.110 us; speedup vs baseline: 1.1055x; 1.1055x over previous
//
#include <hip/hip_runtime.h>
#include <math.h>

// Problem constants (from reference)
#define NNB 16   // neighbors
#define NOB 8    // obstacles
#define SDIM 4   // state dim
#define H1D 64   // hidden 1
#define ED 16    // embedding
#define HPD 64   // psi hidden
#define XW (1 + SDIM + SDIM*NNB + 2*NOB)  // 85 floats per row

__device__ __forceinline__ float fast_rcp(float x) { return __builtin_amdgcn_rcpf(x); }
__device__ __forceinline__ float fast_sqrt(float x) { return __builtin_amdgcn_sqrtf(x); }

// 2*tanh(a), overflow-safe, ~1e-6 rel err (output compared at bf16 granularity)
__device__ __forceinline__ float two_tanh(float a) {
    float ax = fabsf(a);
    float e = __expf(2.0f * ax);          // v_exp_f32 based
    float t = 1.0f - 2.0f * fast_rcp(e + 1.0f);   // tanh(|a|), ->1 as e->inf
    return copysignf(2.0f * t, a);
}

__global__ __launch_bounds__(256) void barrier_net_kernel(
    const float* __restrict__ x,
    const float* __restrict__ Wp1n, const float* __restrict__ bp1n,
    const float* __restrict__ Wp2n, const float* __restrict__ bp2n,
    const float* __restrict__ Wr1n, const float* __restrict__ br1n,
    const float* __restrict__ Wr2n, const float* __restrict__ br2n,
    const float* __restrict__ Wp1o, const float* __restrict__ bp1o,
    const float* __restrict__ Wp2o, const float* __restrict__ bp2o,
    const float* __restrict__ Wr1o, const float* __restrict__ br1o,
    const float* __restrict__ Wr2o, const float* __restrict__ br2o,
    const float* __restrict__ Wpsi1, const float* __restrict__ bpsi1,
    const float* __restrict__ Wpsi2, const float* __restrict__ bpsi2,
    float* __restrict__ out, int nb)
{
    int row = blockIdx.x * blockDim.x + threadIdx.x;
    if (row >= nb) return;
    const float* xr = x + (size_t)row * XW;

    // goal vector
    float g0 = xr[1], g1 = xr[2], g2 = xr[3], g3 = xr[4];

    // ---- load ALL neighbor coords into registers (64 VGPRs) ----
    float e0[NNB], e1[NNB], e2[NNB], e3[NNB];
    #pragma unroll
    for (int n = 0; n < NNB; ++n) {
        e0[n] = xr[1 + SDIM + n*SDIM + 0];
        e1[n] = xr[1 + SDIM + n*SDIM + 1];
        e2[n] = xr[1 + SDIM + n*SDIM + 2];
        e3[n] = xr[1 + SDIM + n*SDIM + 3];
    }
    // ---- obstacle coords (16 VGPRs) ----
    const int obs_off = 1 + SDIM + SDIM*NNB;  // 69
    float o0[NOB], o1[NOB];
    #pragma unroll
    for (int n = 0; n < NOB; ++n) {
        o0[n] = xr[obs_off + n*2 + 0];
        o1[n] = xr[obs_off + n*2 + 1];
    }

    // ---- barrier terms (fast rcp/sqrt; ~1ulp, invisible at bf16 compare) ----
    float barx = 0.f, bary = 0.f;
    #pragma unroll
    for (int n = 0; n < NNB; ++n) {
        float px = -e0[n], py = -e1[n];
        float nrm = fast_sqrt(px*px + py*py);
        float coef = 0.05f * fast_rcp(nrm * (nrm - 0.3f));
        barx += coef * px;
        bary += coef * py;
    }
    #pragma unroll
    for (int n = 0; n < NOB; ++n) {
        float px = -o0[n], py = -o1[n];
        float nrm = fast_sqrt(px*px + py*py);
        float coef = 0.05f * fast_rcp(nrm * (nrm - 0.3f));
        barx += coef * px;
        bary += coef * py;
    }

    // ---------------- neighbor deepset phi, k-outer / n-register-blocked ----
    // phin[j] = sum_n sum_k relu(e_n . W1[:,k] + b1[k]) * W2[k,j]
    float phin[ED];
    #pragma unroll
    for (int j = 0; j < ED; ++j) phin[j] = 0.f;

    for (int k = 0; k < H1D; ++k) {
        float w0 = Wp1n[0*H1D + k], w1 = Wp1n[1*H1D + k];
        float w2 = Wp1n[2*H1D + k], w3 = Wp1n[3*H1D + k];
        float bk = bp1n[k];
        float h[NNB];
        #pragma unroll
        for (int n = 0; n < NNB; ++n) {
            float v = bk + e0[n]*w0 + e1[n]*w1 + e2[n]*w2 + e3[n]*w3;
            h[n] = fmaxf(v, 0.f);
        }
        const float* w2p = Wp2n + k*ED;
        #pragma unroll
        for (int j = 0; j < ED; ++j) {
            float wj = w2p[j];
            float s = phin[j];
            #pragma unroll
            for (int n = 0; n < NNB; ++n) s += h[n] * wj;
            phin[j] = s;
        }
    }
    #pragma unroll
    for (int j = 0; j < ED; ++j) phin[j] += (float)NNB * bp2n[j];

    // ---------------- obstacle deepset phi ---------------------------------
    float phio[ED];
    #pragma unroll
    for (int j = 0; j < ED; ++j) phio[j] = 0.f;

    for (int k = 0; k < H1D; ++k) {
        float w0 = Wp1o[0*H1D + k], w1 = Wp1o[1*H1D + k];
        float bk = bp1o[k];
        float h[NOB];
        #pragma unroll
        for (int n = 0; n < NOB; ++n) {
            float v = bk + o0[n]*w0 + o1[n]*w1;
            h[n] = fmaxf(v, 0.f);
        }
        const float* w2p = Wp2o + k*ED;
        #pragma unroll
        for (int j = 0; j < ED; ++j) {
            float wj = w2p[j];
            float s = phio[j];
            #pragma unroll
            for (int n = 0; n < NOB; ++n) s += h[n] * wj;
            phio[j] = s;
        }
    }
    #pragma unroll
    for (int j = 0; j < ED; ++j) phio[j] += (float)NOB * bp2o[j];

    // ---------------- rho_n = mlp2(phin) -----------------------------------
    float rhon[ED];
    #pragma unroll
    for (int j = 0; j < ED; ++j) rhon[j] = br2n[j];
    #pragma unroll 2
    for (int k = 0; k < H1D; ++k) {
        // 4 partial sums for ILP
        float s0 = br1n[k], s1 = 0.f, s2 = 0.f, s3 = 0.f;
        #pragma unroll
        for (int j = 0; j < ED; j += 4) {
            s0 += phin[j+0] * Wr1n[(j+0)*H1D + k];
            s1 += phin[j+1] * Wr1n[(j+1)*H1D + k];
            s2 += phin[j+2] * Wr1n[(j+2)*H1D + k];
            s3 += phin[j+3] * Wr1n[(j+3)*H1D + k];
        }
        float h = fmaxf((s0 + s1) + (s2 + s3), 0.f);
        const float* w2p = Wr2n + k*ED;
        #pragma unroll
        for (int j = 0; j < ED; ++j) rhon[j] += h * w2p[j];
    }

    // ---------------- rho_o = mlp2(phio) -----------------------------------
    float rhoo[ED];
    #pragma unroll
    for (int j = 0; j < ED; ++j) rhoo[j] = br2o[j];
    #pragma unroll 2
    for (int k = 0; k < H1D; ++k) {
        float s0 = br1o[k], s1 = 0.f, s2 = 0.f, s3 = 0.f;
        #pragma unroll
        for (int j = 0; j < ED; j += 4) {
            s0 += phio[j+0] * Wr1o[(j+0)*H1D + k];
            s1 += phio[j+1] * Wr1o[(j+1)*H1D + k];
            s2 += phio[j+2] * Wr1o[(j+2)*H1D + k];
            s3 += phio[j+3] * Wr1o[(j+3)*H1D + k];
        }
        float h = fmaxf((s0 + s1) + (s2 + s3), 0.f);
        const float* w2p = Wr2o + k*ED;
        #pragma unroll
        for (int j = 0; j < ED; ++j) rhoo[j] += h * w2p[j];
    }

    // ---------------- psi head: h = [rho_n, rho_o, g] (36) -----------------
    float a0 = bpsi2[0], a1 = bpsi2[1];
    #pragma unroll 2
    for (int k = 0; k < HPD; ++k) {
        float s0 = bpsi1[k], s1 = 0.f, s2 = 0.f, s3 = 0.f;
        #pragma unroll
        for (int j = 0; j < ED; j += 4) {
            s0 += rhon[j+0] * Wpsi1[(j+0)*HPD + k];
            s1 += rhon[j+1] * Wpsi1[(j+1)*HPD + k];
            s2 += rhon[j+2] * Wpsi1[(j+2)*HPD + k];
            s3 += rhon[j+3] * Wpsi1[(j+3)*HPD + k];
        }
        #pragma unroll
        for (int j = 0; j < ED; j += 4) {
            s0 += rhoo[j+0] * Wpsi1[(ED+j+0)*HPD + k];
            s1 += rhoo[j+1] * Wpsi1[(ED+j+1)*HPD + k];
            s2 += rhoo[j+2] * Wpsi1[(ED+j+2)*HPD + k];
            s3 += rhoo[j+3] * Wpsi1[(ED+j+3)*HPD + k];
        }
        s0 += g0 * Wpsi1[(2*ED + 0)*HPD + k];
        s1 += g1 * Wpsi1[(2*ED + 1)*HPD + k];
        s2 += g2 * Wpsi1[(2*ED + 2)*HPD + k];
        s3 += g3 * Wpsi1[(2*ED + 3)*HPD + k];
        float h = fmaxf((s0 + s1) + (s2 + s3), 0.f);
        a0 += h * Wpsi2[k*2 + 0];
        a1 += h * Wpsi2[k*2 + 1];
    }

    // emp = 2*tanh(a); action = emp + barrier; normalize
    a0 = two_tanh(a0) + barx;
    a1 = two_tanh(a1) + bary;
    float amax = fmaxf(fabsf(a0), fabsf(a1));
    float inv_alpha = fmaxf(amax * 0.5f, 1.0f);  // A_MAX = 2.0
    float r = fast_rcp(inv_alpha);
    // fast_rcp(1.0) == 1.0 exactly; ~1ulp otherwise — fine at bf16 compare

    out[(size_t)row*2 + 0] = a0 * r;
    out[(size_t)row*2 + 1] = a1 * r;
}

extern "C" void kernel_launch(void* const* d_in, const int* in_sizes, int n_in,
                              void* d_out, int out_size, void* d_ws, size_t ws_size,
                              hipStream_t stream) {
    const float* x     = (const float*)d_in[0];
    const float* Wp1n  = (const float*)d_in[1];
    const float* bp1n  = (const float*)d_in[2];
    const float* Wp2n  = (const float*)d_in[3];
    const float* bp2n  = (const float*)d_in[4];
    const float* Wr1n  = (const float*)d_in[5];
    const float* br1n  = (const float*)d_in[6];
    const float* Wr2n  = (const float*)d_in[7];
    const float* br2n  = (const float*)d_in[8];
    const float* Wp1o  = (const float*)d_in[9];
    const float* bp1o  = (const float*)d_in[10];
    const float* Wp2o  = (const float*)d_in[11];
    const float* bp2o  = (const float*)d_in[12];
    const float* Wr1o  = (const float*)d_in[13];
    const float* br1o  = (const float*)d_in[14];
    const float* Wr2o  = (const float*)d_in[15];
    const float* br2o  = (const float*)d_in[16];
    const float* Wpsi1 = (const float*)d_in[17];
    const float* bpsi1 = (const float*)d_in[18];
    const float* Wpsi2 = (const float*)d_in[19];
    const float* bpsi2 = (const float*)d_in[20];
    float* out = (float*)d_out;

    int nb = in_sizes[0] / XW;   // 131072
    int block = 256;
    int grid = (nb + block - 1) / block;
    barrier_net_kernel<<<grid, block, 0, stream>>>(
        x, Wp1n, bp1n, Wp2n, bp2n, Wr1n, br1n, Wr2n, br2n,
        Wp1o, bp1o, Wp2o, bp2o, Wr1o, br1o, Wr2o, br2o,
        Wpsi1, bpsi1, Wpsi2, bpsi2, out, nb);
}